// Round 7
// baseline (176.871 us; speedup 1.0000x reference)
//
#include <hip/hip_runtime.h>

#define TW 32
#define TH 48
#define HR 58          // TH + 10 intermediate rows
#define IMG_W 512
#define OUT_W 502      // 512 - 11 + 1
#define CH_STRIDE (3 * IMG_W * IMG_W)
#define GX 16
#define GY 11          // ceil(502/48)
#define GZ 16
#define NBLK (GX * GY * GZ)   // 2816

typedef float f2 __attribute__((ext_vector_type(2)));

// v7 = v6 champion (119.8us control) + ONE change: finalize fused via
// last-block ticket. Main body/LDS byte-identical to v6. This bisects the
// v3/v5 VGPR-collapse poison: {MSQ-f4 swizzle} vs {fused finalize}.
// Fixed-order finalize sum -> bitwise identical to the separate kernel.
__global__ __launch_bounds__(256, 4) void ssim_main_kernel(
    const float* __restrict__ sr_img,
    const float* __restrict__ hr_img,
    float* __restrict__ partial,
    unsigned int* __restrict__ ticket,
    float* __restrict__ out)
{
    __shared__ __align__(16) f2    M12[HR][TW + 2];   // 15776 B
    __shared__ __align__(16) f2    SQ [HR][TW + 2];   // 15776 B
    __shared__ __align__(16) float XY [HR][TW + 4];   // 8352 B
    __shared__ float red[4];
    __shared__ unsigned lastflag;                     // total 39924 B -> 4 blk/CU

    const int t  = threadIdx.x;
    const int x0 = blockIdx.x * TW;
    const int y0 = blockIdx.y * TH;
    const int b  = blockIdx.z;

    // 1D separable Gaussian, sigma=1.5, size=11, normalized
    const float Wf[11] = {
        0.00102838f, 0.00759876f, 0.03600077f, 0.10936069f, 0.21300554f,
        0.26601173f,
        0.21300554f, 0.10936069f, 0.03600077f, 0.00759876f, 0.00102838f
    };
    const f2 W2[11] = {
        {0.00102838f,0.00102838f}, {0.00759876f,0.00759876f},
        {0.03600077f,0.03600077f}, {0.10936069f,0.10936069f},
        {0.21300554f,0.21300554f}, {0.26601173f,0.26601173f},
        {0.21300554f,0.21300554f}, {0.10936069f,0.10936069f},
        {0.03600077f,0.03600077f}, {0.00759876f,0.00759876f},
        {0.00102838f,0.00102838f}
    };

    const float* __restrict__ hrp = hr_img + (size_t)b * CH_STRIDE;  // channel 0
    const float* __restrict__ srp = sr_img + (size_t)b * CH_STRIDE;

    // ---------- Phase 1: horizontal 11-tap, direct from global ----------
    if (t < 4 * HR) {             // 232 threads
        int r  = t >> 2;          // 0..57
        int c0 = (t & 3) * 8;     // 0,8,16,24  (output columns / float2 slots)
        int gy = y0 + r; if (gy > IMG_W - 1) gy = IMG_W - 1;
        const float4* hrow = (const float4*)(hrp + (size_t)gy * IMG_W + x0 + c0);
        const float4* srow = (const float4*)(srp + (size_t)gy * IMG_W + x0 + c0);

        f2 hs[20];
#pragma unroll
        for (int q = 0; q < 5; ++q) {
            float4 va = hrow[q];
            float4 vb = srow[q];
            hs[4*q+0] = (f2){va.x, vb.x};
            hs[4*q+1] = (f2){va.y, vb.y};
            hs[4*q+2] = (f2){va.z, vb.z};
            hs[4*q+3] = (f2){va.w, vb.w};
        }

        f2 a12[8], asq[8];
        float axy[8];
#pragma unroll
        for (int j = 0; j < 8; ++j) {
            a12[j] = (f2){0.f, 0.f};
            asq[j] = (f2){0.f, 0.f};
            axy[j] = 0.f;
        }
#pragma unroll
        for (int k = 0; k < 11; ++k) {
            f2 wp = W2[k];
            float wk = Wf[k];
#pragma unroll
            for (int j = 0; j < 8; ++j) {
                f2 x = hs[j + k];
                a12[j] += wp * x;            // v_pk_fma: mu1, mu2
                asq[j] += wp * (x * x);      // v_pk_mul + v_pk_fma: x2, y2
                axy[j]  = fmaf(wk, x.x * x.y, axy[j]);   // scalar: xy
            }
        }
        // stores: float4 = 2 float2 slots; row strides 16B-aligned
        *(float4*)&M12[r][c0+0] = make_float4(a12[0].x,a12[0].y,a12[1].x,a12[1].y);
        *(float4*)&M12[r][c0+2] = make_float4(a12[2].x,a12[2].y,a12[3].x,a12[3].y);
        *(float4*)&M12[r][c0+4] = make_float4(a12[4].x,a12[4].y,a12[5].x,a12[5].y);
        *(float4*)&M12[r][c0+6] = make_float4(a12[6].x,a12[6].y,a12[7].x,a12[7].y);
        *(float4*)&SQ [r][c0+0] = make_float4(asq[0].x,asq[0].y,asq[1].x,asq[1].y);
        *(float4*)&SQ [r][c0+2] = make_float4(asq[2].x,asq[2].y,asq[3].x,asq[3].y);
        *(float4*)&SQ [r][c0+4] = make_float4(asq[4].x,asq[4].y,asq[5].x,asq[5].y);
        *(float4*)&SQ [r][c0+6] = make_float4(asq[6].x,asq[6].y,asq[7].x,asq[7].y);
        *(float4*)&XY [r][c0+0] = make_float4(axy[0],axy[1],axy[2],axy[3]);
        *(float4*)&XY [r][c0+4] = make_float4(axy[4],axy[5],axy[6],axy[7]);
    }
    __syncthreads();

    // ---------- Phase 2: vertical 11-tap, 6-row strips, all 256 threads ----------
    const float C1v = 1e-4f, C2v = 9e-4f;
    float local = 0.f;
    {
        int c  = t & 31;
        int r0 = (t >> 5) * 6;    // 0,6,...,42

        f2 am[6], as_[6];
        float ax[6];
#pragma unroll
        for (int j = 0; j < 6; ++j) {
            am[j] = (f2){0.f, 0.f};
            as_[j] = (f2){0.f, 0.f};
            ax[j] = 0.f;
        }

#pragma unroll
        for (int i = 0; i < 16; ++i) {
            f2 vm = M12[r0 + i][c];      // ds_read_b64
            f2 vs = SQ [r0 + i][c];      // ds_read_b64
            float vx = XY[r0 + i][c];    // ds_read_b32
#pragma unroll
            for (int j = 0; j < 6; ++j) {
                int k = i - j;           // compile-time per (i,j)
                if (k >= 0 && k <= 10) {
                    am[j]  += W2[k] * vm;
                    as_[j] += W2[k] * vs;
                    ax[j]   = fmaf(Wf[k], vx, ax[j]);
                }
            }
        }

        int ox = x0 + c;
#pragma unroll
        for (int j = 0; j < 6; ++j) {
            int oy = y0 + r0 + j;
            if (oy < OUT_W && ox < OUT_W) {
                float m1 = am[j].x, m2 = am[j].y;
                float mu1s = m1 * m1, mu2s = m2 * m2, m12 = m1 * m2;
                float s1 = as_[j].x - mu1s, s2 = as_[j].y - mu2s, s12 = ax[j] - m12;
                float num = (2.f * m12 + C1v) * (2.f * s12 + C2v);
                float den = (mu1s + mu2s + C1v) * (s1 + s2 + C2v);
                local += num / den;
            }
        }
    }

    // ---------- Block reduction ----------
#pragma unroll
    for (int off = 32; off > 0; off >>= 1)
        local += __shfl_down(local, off);
    if ((t & 63) == 0) red[t >> 6] = local;
    __syncthreads();

    const int blk = (blockIdx.z * GY + blockIdx.y) * GX + blockIdx.x;
    if (t == 0) {
        partial[blk] = red[0] + red[1] + red[2] + red[3];
        __threadfence();                       // release partial[] device-wide
        unsigned old = atomicAdd(ticket, 1u);  // device-scope
        lastflag = (old == NBLK - 1) ? 1u : 0u;
    }
    __syncthreads();

    // ---------- Fused finalize: last block, fixed-order (deterministic) ----------
    if (lastflag) {
        __threadfence();                       // acquire all partial[] stores
        float s = 0.f;
#pragma unroll
        for (int i = 0; i < NBLK / 256; ++i)   // 11 iterations
            s += partial[t + i * 256];
#pragma unroll
        for (int off = 32; off > 0; off >>= 1)
            s += __shfl_down(s, off);
        if ((t & 63) == 0) red[t >> 6] = s;
        __syncthreads();
        if (t == 0)
            out[0] = (red[0] + red[1] + red[2] + red[3]) * (1.0f / (16.0f * 502.0f * 502.0f));
    }
}

extern "C" void kernel_launch(void* const* d_in, const int* in_sizes, int n_in,
                              void* d_out, int out_size, void* d_ws, size_t ws_size,
                              hipStream_t stream)
{
    const float* sr = (const float*)d_in[0];  // sr_image
    const float* hr = (const float*)d_in[1];  // hr_image
    float* out = (float*)d_out;
    float* partial = (float*)d_ws;                               // 2816 floats
    unsigned int* ticket = (unsigned int*)((char*)d_ws + 16384); // past partial[]

    hipMemsetAsync(ticket, 0, 4, stream);     // capture-safe 4B memset node
    dim3 grid(GX, GY, GZ);
    ssim_main_kernel<<<grid, 256, 0, stream>>>(sr, hr, partial, ticket, out);
}

// Round 8
// 118.832 us; speedup vs baseline: 1.4884x; 1.4884x over previous
//
#include <hip/hip_runtime.h>

#define TW 32
#define TH 48
#define HR 58          // TH + 10 intermediate rows
#define IMG_W 512
#define OUT_W 502      // 512 - 11 + 1
#define CH_STRIDE (3 * IMG_W * IMG_W)
#define GX 16
#define GY 11          // ceil(502/48)
#define GZ 16
#define NBLK (GX * GY * GZ)   // 2816
#define MSQS 35        // MSQ row stride in f4 slots (cm(31)=34 -> 35)

typedef float f2 __attribute__((ext_vector_type(2)));
typedef float f4 __attribute__((ext_vector_type(4)));

// v8 = v6 champion + ONLY the MSQ-f4 merged/swizzled LDS layout (second arm
// of the bisect, now isolated). v7 proved the fused-finalize tail alone
// collapses regalloc (VGPR 56, main 88us) -> finalize stays a separate
// kernel, permanently. MSQ change: phase-2 row-read = b128+b32 (was
// b64+b64+b32, -16 issues/thread); phase-1 10 LDS stores -> 8 f4 + 2 f4.
// Swizzle cm(c)=c+(c>>3) balances banks (stores 8-avg, reads 4-avg).
__global__ __launch_bounds__(256, 4) void ssim_main_kernel(
    const float* __restrict__ sr_img,
    const float* __restrict__ hr_img,
    float* __restrict__ partial)
{
    __shared__ __align__(16) f4    MSQ[HR][MSQS];   // {m1,m2,x2,y2}  32480 B
    __shared__ __align__(16) float XY [HR][TW + 4]; // xy              8352 B
    __shared__ float red[4];                        // 40848 B -> 4 blk/CU

    const int t  = threadIdx.x;
    const int x0 = blockIdx.x * TW;
    const int y0 = blockIdx.y * TH;
    const int b  = blockIdx.z;

    // 1D separable Gaussian, sigma=1.5, size=11, normalized
    const float Wf[11] = {
        0.00102838f, 0.00759876f, 0.03600077f, 0.10936069f, 0.21300554f,
        0.26601173f,
        0.21300554f, 0.10936069f, 0.03600077f, 0.00759876f, 0.00102838f
    };
    const f2 W2[11] = {
        {0.00102838f,0.00102838f}, {0.00759876f,0.00759876f},
        {0.03600077f,0.03600077f}, {0.10936069f,0.10936069f},
        {0.21300554f,0.21300554f}, {0.26601173f,0.26601173f},
        {0.21300554f,0.21300554f}, {0.10936069f,0.10936069f},
        {0.03600077f,0.03600077f}, {0.00759876f,0.00759876f},
        {0.00102838f,0.00102838f}
    };

    const float* __restrict__ hrp = hr_img + (size_t)b * CH_STRIDE;  // channel 0
    const float* __restrict__ srp = sr_img + (size_t)b * CH_STRIDE;

    // ---------- Phase 1: horizontal 11-tap, direct from global ----------
    if (t < 4 * HR) {             // 232 threads
        int r  = t >> 2;          // 0..57
        int c0 = (t & 3) * 8;     // 0,8,16,24
        int gy = y0 + r; if (gy > IMG_W - 1) gy = IMG_W - 1;
        const float4* hrow = (const float4*)(hrp + (size_t)gy * IMG_W + x0 + c0);
        const float4* srow = (const float4*)(srp + (size_t)gy * IMG_W + x0 + c0);

        f2 hs[20];
#pragma unroll
        for (int q = 0; q < 5; ++q) {
            float4 va = hrow[q];
            float4 vb = srow[q];
            hs[4*q+0] = (f2){va.x, vb.x};
            hs[4*q+1] = (f2){va.y, vb.y};
            hs[4*q+2] = (f2){va.z, vb.z};
            hs[4*q+3] = (f2){va.w, vb.w};
        }

        f2 a12[8], asq[8];
        float axy[8];
#pragma unroll
        for (int j = 0; j < 8; ++j) {
            a12[j] = (f2){0.f, 0.f};
            asq[j] = (f2){0.f, 0.f};
            axy[j] = 0.f;
        }
#pragma unroll
        for (int k = 0; k < 11; ++k) {
            f2 wp = W2[k];
            float wk = Wf[k];
#pragma unroll
            for (int j = 0; j < 8; ++j) {
                f2 x = hs[j + k];
                a12[j] += wp * x;            // v_pk_fma: mu1, mu2
                asq[j] += wp * (x * x);      // v_pk_mul + v_pk_fma: x2, y2
                axy[j]  = fmaf(wk, x.x * x.y, axy[j]);   // scalar: xy
            }
        }

        int cb = c0 + (c0 >> 3);             // swizzled column base (0,9,18,27)
#pragma unroll
        for (int u = 0; u < 8; ++u)
            MSQ[r][cb + u] = (f4){a12[u].x, a12[u].y, asq[u].x, asq[u].y};
        *(float4*)&XY[r][c0]   = make_float4(axy[0],axy[1],axy[2],axy[3]);
        *(float4*)&XY[r][c0+4] = make_float4(axy[4],axy[5],axy[6],axy[7]);
    }
    __syncthreads();

    // ---------- Phase 2: vertical 11-tap, 6-row strips, all 256 threads ----------
    const float C1v = 1e-4f, C2v = 9e-4f;
    float local = 0.f;
    {
        int c  = t & 31;
        int r0 = (t >> 5) * 6;    // 0,6,...,42
        int cs = c + (c >> 3);    // swizzled read column

        f2 am[6], as_[6];
        float ax[6];
#pragma unroll
        for (int j = 0; j < 6; ++j) {
            am[j] = (f2){0.f, 0.f};
            as_[j] = (f2){0.f, 0.f};
            ax[j] = 0.f;
        }

#pragma unroll
        for (int i = 0; i < 16; ++i) {
            f4 v = MSQ[r0 + i][cs];        // ds_read_b128
            float vx = XY[r0 + i][c];      // ds_read_b32
            f2 vm = (f2){v.x, v.y};
            f2 vs = (f2){v.z, v.w};
#pragma unroll
            for (int j = 0; j < 6; ++j) {
                int k = i - j;             // compile-time per (i,j)
                if (k >= 0 && k <= 10) {
                    am[j]  += W2[k] * vm;
                    as_[j] += W2[k] * vs;
                    ax[j]   = fmaf(Wf[k], vx, ax[j]);
                }
            }
        }

        int ox = x0 + c;
#pragma unroll
        for (int j = 0; j < 6; ++j) {
            int oy = y0 + r0 + j;
            if (oy < OUT_W && ox < OUT_W) {
                float m1 = am[j].x, m2 = am[j].y;
                float mu1s = m1 * m1, mu2s = m2 * m2, m12 = m1 * m2;
                float s1 = as_[j].x - mu1s, s2 = as_[j].y - mu2s, s12 = ax[j] - m12;
                float num = (2.f * m12 + C1v) * (2.f * s12 + C2v);
                float den = (mu1s + mu2s + C1v) * (s1 + s2 + C2v);
                local += num / den;
            }
        }
    }

    // ---------- Reduction: wave shuffle + tiny LDS ----------
#pragma unroll
    for (int off = 32; off > 0; off >>= 1)
        local += __shfl_down(local, off);
    if ((t & 63) == 0) red[t >> 6] = local;
    __syncthreads();
    if (t == 0) {
        int blk = (blockIdx.z * GY + blockIdx.y) * GX + blockIdx.x;
        partial[blk] = red[0] + red[1] + red[2] + red[3];
    }
}

__global__ __launch_bounds__(256) void ssim_finalize(
    const float* __restrict__ partial, float* __restrict__ out)
{
    __shared__ float red[4];
    int t = threadIdx.x;
    float s = 0.f;
#pragma unroll
    for (int i = 0; i < NBLK / 256; ++i)       // 11 iterations
        s += partial[t + i * 256];
#pragma unroll
    for (int off = 32; off > 0; off >>= 1)
        s += __shfl_down(s, off);
    if ((t & 63) == 0) red[t >> 6] = s;
    __syncthreads();
    if (t == 0)
        out[0] = (red[0] + red[1] + red[2] + red[3]) * (1.0f / (16.0f * 502.0f * 502.0f));
}

extern "C" void kernel_launch(void* const* d_in, const int* in_sizes, int n_in,
                              void* d_out, int out_size, void* d_ws, size_t ws_size,
                              hipStream_t stream)
{
    const float* sr = (const float*)d_in[0];  // sr_image
    const float* hr = (const float*)d_in[1];  // hr_image
    float* out = (float*)d_out;
    float* partial = (float*)d_ws;            // 2816 floats, fully overwritten

    dim3 grid(GX, GY, GZ);
    ssim_main_kernel<<<grid, 256, 0, stream>>>(sr, hr, partial);
    ssim_finalize<<<1, 256, 0, stream>>>(partial, out);
}